// Round 3
// baseline (128.584 us; speedup 1.0000x reference)
//
#include <hip/hip_runtime.h>

// GNNDiscriminator: fused GATConv + mean-pool + linear head.
//
// Identities (outputs are only (out, gf); per-node out_nodes never needed):
//   a_src[v] = x[v] . u_src,  u_src = W_lin @ att_src   (precomputed, kernel 1)
//   a_dst[v] = x[v] . u_dst
//   a_edge[e] = eattr[e] . we, we = W_edge @ att_edge
//   gf = ((r^T x) @ W_lin) / V + b_gat,  r[s] = sum of attn weights leaving s
// Softmax computed WITHOUT the segment-max shift: alpha ~ N(0,~2) by weight
// scaling, |alpha| < 9 over all edges -> exp(alpha) is safe in fp32 and the
// normalized ratio is identical (threshold headroom 10x).
//
// One WAVE per graph (4/block) -> zero __syncthreads; per-wave LDS state only,
// ordered by the wave's in-order LDS pipe (__threadfence_block = lgkmcnt wait).

#define BB   4096
#define VV   32
#define FF   16
#define NBB  8
#define CC   128
#define EPER 256
constexpr int NTOT  = BB * VV;
constexpr int ERAND = BB * EPER;
constexpr int ETOT  = ERAND + NTOT;
constexpr float SLOPE = 0.2f;

// ---- kernel 1: u_src[16], u_dst[16], we[8] into ws (one 64-thread block) ----
__launch_bounds__(64)
__global__ void gnn_precompute(const float* __restrict__ W_lin,
                               const float* __restrict__ att_src,
                               const float* __restrict__ att_dst,
                               const float* __restrict__ W_edge,
                               const float* __restrict__ att_edge,
                               float* __restrict__ ws)
{
  const int l = threadIdx.x;
  const float2 as = ((const float2*)att_src)[l];
  const float2 ad = ((const float2*)att_dst)[l];
  const float2 ae = ((const float2*)att_edge)[l];
  #pragma unroll
  for (int f = 0; f < FF; ++f) {
    const float2 w = ((const float2*)W_lin)[f * 64 + l];
    float ps = w.x * as.x + w.y * as.y;
    float pd = w.x * ad.x + w.y * ad.y;
    #pragma unroll
    for (int m = 1; m <= 32; m <<= 1) { ps += __shfl_xor(ps, m); pd += __shfl_xor(pd, m); }
    if (l == 0) { ws[f] = ps; ws[FF + f] = pd; }
  }
  #pragma unroll
  for (int f = 0; f < NBB; ++f) {
    const float2 w = ((const float2*)W_edge)[f * 64 + l];
    float pe = w.x * ae.x + w.y * ae.y;
    #pragma unroll
    for (int m = 1; m <= 32; m <<= 1) pe += __shfl_xor(pe, m);
    if (l == 0) ws[2 * FF + f] = pe;
  }
}

// ---- kernel 2: one wave per graph ----
__launch_bounds__(256, 4)
__global__ void gnn_main(const float* __restrict__ x,
                         const int*   __restrict__ eidx,
                         const float* __restrict__ eattr,
                         const float* __restrict__ W_lin,
                         const float* __restrict__ b_gat,
                         const float* __restrict__ W_out,
                         const float* __restrict__ b_out,
                         const float* __restrict__ ws,
                         float* __restrict__ out,
                         float* __restrict__ gf_out)
{
  const int t    = threadIdx.x;
  const int lane = t & 63;
  const int wave = __builtin_amdgcn_readfirstlane(t) >> 6;   // uniform
  const int g    = blockIdx.x * 4 + wave;

  __shared__ float s_asrc[4][VV], s_adst[4][VV];
  __shared__ float s_den[4][VV];
  __shared__ float s_r[4][VV];
  __shared__ float s_xt[4][FF * 33];     // transposed r-scaled x, pad 33

  if (lane < VV) { s_den[wave][lane] = 0.f; s_r[wave][lane] = 0.f; }

  // ---- x rows first: they head the critical path (x -> a -> alpha) ----
  float xr[FF] = {};
  if (lane < VV) {
    const float* xp = x + (size_t)(g * VV + lane) * FF;
    #pragma unroll
    for (int f = 0; f < FF; ++f) xr[f] = xp[f];          // 4x dwordx4
  }

  // ---- edges: 4 CONTIGUOUS edges per lane (int4 idx, 128B eattr/lane) ----
  int es[4], ed[4];
  const int4 s4 = ((const int4*)(eidx + g * EPER))[lane];
  const int4 d4 = ((const int4*)(eidx + ETOT + g * EPER))[lane];
  es[0] = s4.x - g * VV; es[1] = s4.y - g * VV; es[2] = s4.z - g * VV; es[3] = s4.w - g * VV;
  ed[0] = d4.x - g * VV; ed[1] = d4.y - g * VV; ed[2] = d4.z - g * VV; ed[3] = d4.w - g * VV;
  float4 ea[8];
  {
    const float4* ap = (const float4*)(eattr + (size_t)(g * EPER + 4 * lane) * NBB);
    #pragma unroll
    for (int j = 0; j < 8; ++j) ea[j] = ap[j];
  }
  // self-loop edge for node (lane-32), handled by the upper half-wave
  float4 la0 = {0,0,0,0}, la1 = {0,0,0,0};
  if (lane >= VV) {
    const float4* lp = (const float4*)(eattr + (size_t)(ERAND + g * VV + (lane - VV)) * NBB);
    la0 = lp[0]; la1 = lp[1];
  }

  // ---- phase A: a_src/a_dst via precomputed u-vectors (lanes 0-31) ----
  if (lane < VV) {
    float a0 = 0.f, a1 = 0.f;
    #pragma unroll
    for (int f = 0; f < FF; ++f) { a0 += xr[f] * ws[f]; a1 += xr[f] * ws[FF + f]; }
    s_asrc[wave][lane] = a0; s_adst[wave][lane] = a1;
  }
  __threadfence_block();

  // ---- phase B: ex = exp(leaky(alpha)), accumulate denom per dst ----
  const float w0 = ws[32], w1 = ws[33], w2 = ws[34], w3 = ws[35];
  const float w4 = ws[36], w5 = ws[37], w6 = ws[38], w7 = ws[39];
  float ex[5];
  #pragma unroll
  for (int k = 0; k < 4; ++k) {
    const float aed = ea[2*k].x*w0 + ea[2*k].y*w1 + ea[2*k].z*w2 + ea[2*k].w*w3
                    + ea[2*k+1].x*w4 + ea[2*k+1].y*w5 + ea[2*k+1].z*w6 + ea[2*k+1].w*w7;
    const float a  = s_asrc[wave][es[k]] + s_adst[wave][ed[k]] + aed;
    const float al = a > 0.f ? a : SLOPE * a;
    ex[k] = __expf(al);
    atomicAdd(&s_den[wave][ed[k]], ex[k]);
  }
  ex[4] = 0.f;
  if (lane >= VV) {
    const int v = lane - VV;
    const float aed = la0.x*w0 + la0.y*w1 + la0.z*w2 + la0.w*w3
                    + la1.x*w4 + la1.y*w5 + la1.z*w6 + la1.w*w7;
    const float a  = s_asrc[wave][v] + s_adst[wave][v] + aed;
    const float al = a > 0.f ? a : SLOPE * a;
    ex[4] = __expf(al);
    atomicAdd(&s_den[wave][v], ex[4]);
  }
  __threadfence_block();

  // ---- phase C: r[s] += ex * rcp(denom[dst])  (no separate invert round) ----
  #pragma unroll
  for (int k = 0; k < 4; ++k)
    atomicAdd(&s_r[wave][es[k]], ex[k] * __builtin_amdgcn_rcpf(s_den[wave][ed[k]]));
  if (lane >= VV) {
    const int v = lane - VV;
    atomicAdd(&s_r[wave][v], ex[4] * __builtin_amdgcn_rcpf(s_den[wave][v]));
  }
  __threadfence_block();

  // ---- phase D: y = r^T x / V  (transposed scaled rows, <=2-way banked) ----
  if (lane < VV) {
    const float rl = s_r[wave][lane];
    #pragma unroll
    for (int f = 0; f < FF; ++f) s_xt[wave][f * 33 + lane] = xr[f] * rl;
  }
  __threadfence_block();
  const int fy = lane & 15, part = lane >> 4;
  float yp = 0.f;
  #pragma unroll
  for (int j = 0; j < 8; ++j) yp += s_xt[wave][fy * 33 + part * 8 + j];
  yp += __shfl_xor(yp, 16);
  yp += __shfl_xor(yp, 32);
  yp *= (1.0f / VV);                 // lane holds y[lane&15] / V

  // ---- gf = y @ W_lin + b_gat ; out = gf . W_out + b_out ----
  const float2 bg = ((const float2*)b_gat)[lane];
  float gx = bg.x, gy = bg.y;
  const float2* W2 = (const float2*)W_lin;
  #pragma unroll
  for (int f = 0; f < FF; ++f) {
    const float yf = __shfl(yp, f);                  // y[f] broadcast
    const float2 w = W2[f * 64 + lane];
    gx += yf * w.x; gy += yf * w.y;
  }
  ((float2*)(gf_out + (size_t)g * CC))[lane] = make_float2(gx, gy);

  const float2 wo = ((const float2*)W_out)[lane];
  float p = gx * wo.x + gy * wo.y;
  #pragma unroll
  for (int m = 1; m <= 32; m <<= 1) p += __shfl_xor(p, m);
  if (lane == 0) out[g] = p + b_out[0];
}

extern "C" void kernel_launch(void* const* d_in, const int* in_sizes, int n_in,
                              void* d_out, int out_size, void* d_ws, size_t ws_size,
                              hipStream_t stream) {
  const float* x        = (const float*)d_in[0];
  const int*   eidx     = (const int*)  d_in[1];
  const float* eattr    = (const float*)d_in[2];
  const float* W_lin    = (const float*)d_in[3];
  const float* att_src  = (const float*)d_in[4];
  const float* att_dst  = (const float*)d_in[5];
  const float* att_edge = (const float*)d_in[6];
  const float* W_edge   = (const float*)d_in[7];
  const float* b_gat    = (const float*)d_in[8];
  const float* W_out    = (const float*)d_in[9];
  const float* b_out    = (const float*)d_in[10];

  float* ws  = (float*)d_ws;         // [0:16) u_src, [16:32) u_dst, [32:40) we
  float* out = (float*)d_out;        // [B,1] first, then gf [B,C]
  float* gf  = out + BB;

  gnn_precompute<<<dim3(1), dim3(64), 0, stream>>>(W_lin, att_src, att_dst,
                                                   W_edge, att_edge, ws);
  gnn_main<<<dim3(BB / 4), dim3(256), 0, stream>>>(
      x, eidx, eattr, W_lin, b_gat, W_out, b_out, ws, out, gf);
}

// Round 4
// 117.491 us; speedup vs baseline: 1.0944x; 1.0944x over previous
//
#include <hip/hip_runtime.h>

// GNNDiscriminator: fully-fused single kernel. One WAVE per graph (4/block),
// zero __syncthreads, zero cross-wave traffic. Each wave redundantly computes
// the tiny projections u_src/u_dst/we (L1-hot weights) instead of a separate
// serial precompute kernel + global ws round-trip.
//
// Identities:
//   a_src[v] = x[v].u_src, u_src = W_lin@att_src ; a_dst likewise
//   a_edge[e] = eattr[e].we, we = W_edge@att_edge
//   softmax without max-shift (|alpha|<9 by weight scaling; fp32-safe)
//   gf = ((r^T x) @ W_lin)/V + b_gat,  r[s] = sum of attn weights leaving s
//
// Intra-wave LDS ordering: DS pipe is in-order per wave; __threadfence_block
// (lgkmcnt/vmcnt drain) between phases pins compiler ordering.

#define BB   4096
#define VV   32
#define FF   16
#define NBB  8
#define CC   128
#define EPER 256
constexpr int NTOT  = BB * VV;
constexpr int ERAND = BB * EPER;
constexpr int ETOT  = ERAND + NTOT;
constexpr float SLOPE = 0.2f;

__launch_bounds__(256, 4)
__global__ void gnn_all(const float* __restrict__ x,
                        const int*   __restrict__ eidx,
                        const float* __restrict__ eattr,
                        const float* __restrict__ W_lin,
                        const float* __restrict__ att_src,
                        const float* __restrict__ att_dst,
                        const float* __restrict__ att_edge,
                        const float* __restrict__ W_edge,
                        const float* __restrict__ b_gat,
                        const float* __restrict__ W_out,
                        const float* __restrict__ b_out,
                        float* __restrict__ out,
                        float* __restrict__ gf_out)
{
  const int t    = threadIdx.x;
  const int lane = t & 63;
  const int wave = __builtin_amdgcn_readfirstlane(t) >> 6;   // uniform
  const int g    = blockIdx.x * 4 + wave;
  const int half = lane >> 5;          // 0/1: feature half of the owned row
  const int v    = lane & 31;          // owned node

  __shared__ float2 s_a[4][VV];                    // {a_src, a_dst}
  __shared__ float  s_den[4][VV];
  __shared__ float  s_r[4][VV];
  __shared__ float2 s_uv[4][FF];                   // {u_src[f], u_dst[f]}
  __shared__ __align__(16) float s_we[4][NBB];
  __shared__ float  s_xt[4][FF * 33];              // transposed r-scaled x
  __shared__ __align__(16) float s_y[4][FF];

  // ---- global loads, all issued up front ----
  // x row v, split: this lane holds features half*8 .. half*8+7
  float4 xa, xb;
  {
    const float* xp = x + (size_t)(g * VV + v) * FF + half * 8;
    xa = ((const float4*)xp)[0]; xb = ((const float4*)xp)[1];
  }
  // 4 edges per lane, lane-interleaved (fully coalesced)
  int es[4], ed[4];
  float4 ea0[4], ea1[4];
  #pragma unroll
  for (int k = 0; k < 4; ++k) {
    const int e = g * EPER + 64 * k + lane;
    es[k] = eidx[e] - g * VV;
    ed[k] = eidx[ETOT + e] - g * VV;
    const float4* ap = (const float4*)(eattr + (size_t)e * NBB);
    ea0[k] = ap[0]; ea1[k] = ap[1];
  }
  // self-loop edge for node v: upper half-wave
  float4 la0 = {0,0,0,0}, la1 = {0,0,0,0};
  if (half) {
    const float4* lp = (const float4*)(eattr + (size_t)(ERAND + g * VV + v) * NBB);
    la0 = lp[0]; la1 = lp[1];
  }

  // ---- in-wave projections: u_src/u_dst (all 64 lanes: f=lane&15, q=lane>>4) ----
  {
    const int fu = lane & 15, q = lane >> 4;
    const float4* wr = (const float4*)(W_lin + fu * CC + q * 32);
    const float4* as = (const float4*)(att_src + q * 32);
    const float4* ad = (const float4*)(att_dst + q * 32);
    float us = 0.f, ud = 0.f;
    #pragma unroll
    for (int j = 0; j < 8; ++j) {
      const float4 w = wr[j], a = as[j], d = ad[j];
      us += w.x*a.x + w.y*a.y + w.z*a.z + w.w*a.w;
      ud += w.x*d.x + w.y*d.y + w.z*d.z + w.w*d.w;
    }
    us += __shfl_xor(us, 16); us += __shfl_xor(us, 32);
    ud += __shfl_xor(ud, 16); ud += __shfl_xor(ud, 32);
    if (lane < FF) s_uv[wave][lane] = make_float2(us, ud);
  }
  // we[8]: lower half-wave (f=lane&7, oct=lane>>3)
  if (!half) {
    const int f8 = v & 7, oct = v >> 3;
    const float4* wr = (const float4*)(W_edge + f8 * CC + oct * 32);
    const float4* ae = (const float4*)(att_edge + oct * 32);
    float pe = 0.f;
    #pragma unroll
    for (int j = 0; j < 8; ++j) {
      const float4 w = wr[j], a = ae[j];
      pe += w.x*a.x + w.y*a.y + w.z*a.z + w.w*a.w;
    }
    pe += __shfl_xor(pe, 8); pe += __shfl_xor(pe, 16);
    if (v < NBB) s_we[wave][v] = pe;
  }

  // ---- a_src/a_dst: half-row dot with u (LDS-broadcast), combine halves ----
  float a0 = 0.f, a1 = 0.f;
  {
    const float xr[8] = {xa.x, xa.y, xa.z, xa.w, xb.x, xb.y, xb.z, xb.w};
    #pragma unroll
    for (int j = 0; j < 8; ++j) {
      const float2 u = s_uv[wave][half * 8 + j];   // 2 addrs/instr: conflict-free
      a0 += xr[j] * u.x; a1 += xr[j] * u.y;
    }
  }
  a0 += __shfl_xor(a0, 32); a1 += __shfl_xor(a1, 32);
  if (!half) {
    s_a[wave][v] = make_float2(a0, a1);
    s_den[wave][v] = 0.f; s_r[wave][v] = 0.f;
  }
  __threadfence_block();

  // ---- phase B: ex = exp(leaky(alpha)), accumulate denom per dst ----
  const float4 w03 = *(const float4*)&s_we[wave][0];
  const float4 w47 = *(const float4*)&s_we[wave][4];
  float ex[5];
  #pragma unroll
  for (int k = 0; k < 4; ++k) {
    const float2 A = s_a[wave][es[k]];
    const float2 D = s_a[wave][ed[k]];
    const float aed = ea0[k].x*w03.x + ea0[k].y*w03.y + ea0[k].z*w03.z + ea0[k].w*w03.w
                    + ea1[k].x*w47.x + ea1[k].y*w47.y + ea1[k].z*w47.z + ea1[k].w*w47.w;
    const float a  = A.x + D.y + aed;
    const float al = a > 0.f ? a : SLOPE * a;
    ex[k] = __expf(al);
    atomicAdd(&s_den[wave][ed[k]], ex[k]);
  }
  ex[4] = 0.f;
  if (half) {
    const float2 S = s_a[wave][v];
    const float aed = la0.x*w03.x + la0.y*w03.y + la0.z*w03.z + la0.w*w03.w
                    + la1.x*w47.x + la1.y*w47.y + la1.z*w47.z + la1.w*w47.w;
    const float a  = S.x + S.y + aed;
    const float al = a > 0.f ? a : SLOPE * a;
    ex[4] = __expf(al);
    atomicAdd(&s_den[wave][v], ex[4]);
  }
  __threadfence_block();

  // ---- phase C: r[src] += ex * rcp(denom[dst]) ----
  #pragma unroll
  for (int k = 0; k < 4; ++k)
    atomicAdd(&s_r[wave][es[k]], ex[k] * __builtin_amdgcn_rcpf(s_den[wave][ed[k]]));
  if (half)
    atomicAdd(&s_r[wave][v], ex[4] * __builtin_amdgcn_rcpf(s_den[wave][v]));
  __threadfence_block();

  // ---- phase D: y = r^T x / V via transposed scaled rows ----
  {
    const float rl = s_r[wave][v];                 // 2-way broadcast: free
    const float xr[8] = {xa.x, xa.y, xa.z, xa.w, xb.x, xb.y, xb.z, xb.w};
    #pragma unroll
    for (int j = 0; j < 8; ++j)
      s_xt[wave][(half * 8 + j) * 33 + v] = xr[j] * rl;
  }
  __threadfence_block();
  {
    const int fy = lane & 15, part = lane >> 4;
    float yp = 0.f;
    #pragma unroll
    for (int j = 0; j < 8; ++j) yp += s_xt[wave][fy * 33 + part * 8 + j];
    yp += __shfl_xor(yp, 16); yp += __shfl_xor(yp, 32);
    if (lane < FF) s_y[wave][lane] = yp * (1.0f / VV);
  }
  __threadfence_block();

  // ---- gf = y @ W_lin + b_gat ; out = gf . W_out + b_out ----
  const float4 y03 = *(const float4*)&s_y[wave][0];
  const float4 y47 = *(const float4*)&s_y[wave][4];
  const float4 y8b = *(const float4*)&s_y[wave][8];
  const float4 ycf = *(const float4*)&s_y[wave][12];
  const float yv[16] = {y03.x,y03.y,y03.z,y03.w, y47.x,y47.y,y47.z,y47.w,
                        y8b.x,y8b.y,y8b.z,y8b.w, ycf.x,ycf.y,ycf.z,ycf.w};
  const float2 bg = ((const float2*)b_gat)[lane];
  float gx = bg.x, gy = bg.y;
  const float2* W2 = (const float2*)W_lin;
  #pragma unroll
  for (int f = 0; f < FF; ++f) {
    const float2 w = W2[f * 64 + lane];            // L1-hot after first wave
    gx += yv[f] * w.x; gy += yv[f] * w.y;
  }
  ((float2*)(gf_out + (size_t)g * CC))[lane] = make_float2(gx, gy);

  const float2 wo = ((const float2*)W_out)[lane];
  float p = gx * wo.x + gy * wo.y;
  #pragma unroll
  for (int m = 1; m <= 32; m <<= 1) p += __shfl_xor(p, m);
  if (lane == 0) out[g] = p + b_out[0];
}

extern "C" void kernel_launch(void* const* d_in, const int* in_sizes, int n_in,
                              void* d_out, int out_size, void* d_ws, size_t ws_size,
                              hipStream_t stream) {
  const float* x        = (const float*)d_in[0];
  const int*   eidx     = (const int*)  d_in[1];
  const float* eattr    = (const float*)d_in[2];
  const float* W_lin    = (const float*)d_in[3];
  const float* att_src  = (const float*)d_in[4];
  const float* att_dst  = (const float*)d_in[5];
  const float* att_edge = (const float*)d_in[6];
  const float* W_edge   = (const float*)d_in[7];
  const float* b_gat    = (const float*)d_in[8];
  const float* W_out    = (const float*)d_in[9];
  const float* b_out    = (const float*)d_in[10];

  float* out = (float*)d_out;        // [B,1] first, then gf [B,C]
  float* gf  = out + BB;

  gnn_all<<<dim3(BB / 4), dim3(256), 0, stream>>>(
      x, eidx, eattr, W_lin, att_src, att_dst, att_edge, W_edge,
      b_gat, W_out, b_out, out, gf);
}